// Round 8
// baseline (186.827 us; speedup 1.0000x reference)
//
#include <hip/hip_runtime.h>
#include <math.h>

// ComplexGaussianRasterizer — fused bucket-bin (batched atomics) + LDS-staged
// voxel-gather.
// Path A (ws permitting):
//   K1 prep_fused: per gaussian -> 48B record (quad coeffs pre-scaled by
//                  log2e); 27 bin slots fully unrolled: phase 1 issues all
//                  predicated atomicAdds (pipelined), phase 2 stores ids.
//   K2 eval_lds:   one wave per 4^3 subtile, one voxel per lane. Wave stages
//                  64 records/chunk into wave-private LDS (coalesced float4
//                  loads, no barriers), inner loop = broadcast ds_read_b128 +
//                  ~25 VALU + exp2. Register accumulate, coalesced store.
// Path B (fallback): round-5 compact-list pipeline (exp2-consistent).

#define RES     128
#define SB      4
#define NSBA    32
#define NTILE   (NSBA * NSBA * NSBA)   // 32768
#define RECSZ   12                     // floats per record (48 B)
#define CAP     96                     // bucket capacity (lambda~47 interior)
#define LIST_CAP 1500000               // path-B compact list cap

// ---------------- record builder (quad coeffs scaled by log2e) -------------
__device__ __forceinline__ void build_record(
    const float* means, const float* opacities, const float* scales,
    const float* rotations, const float* phases, const float* phases_add,
    float* rec, int g, int* bxo, int* byo, int* bzo)
{
    const float LB   = -1.0f;
    const float VOX  = 2.0f / 128.0f;
    const float L2E  = 1.4426950408889634f;

    float mx = means[g*3+0], my = means[g*3+1], mz = means[g*3+2];
    float op = opacities[g];
    float sx = scales[g*3+0], sy = scales[g*3+1], sz = scales[g*3+2];
    float qw = rotations[g*4+0], qx = rotations[g*4+1],
          qy = rotations[g*4+2], qz = rotations[g*4+3];
    float ph = phases[g], pa = phases_add[g];

    float qn = rsqrtf(qw*qw + qx*qx + qy*qy + qz*qz);
    qw *= qn; qx *= qn; qy *= qn; qz *= qn;

    float r00 = 1.0f - 2.0f*(qy*qy + qz*qz);
    float r01 = 2.0f*(qx*qy - qw*qz);
    float r02 = 2.0f*(qx*qz + qw*qy);
    float r10 = 2.0f*(qx*qy + qw*qz);
    float r11 = 1.0f - 2.0f*(qx*qx + qz*qz);
    float r12 = 2.0f*(qy*qz - qw*qx);
    float r20 = 2.0f*(qx*qz - qw*qy);
    float r21 = 2.0f*(qy*qz + qw*qx);
    float r22 = 1.0f - 2.0f*(qx*qx + qy*qy);

    float m00 = r00*sx, m01 = r01*sy, m02 = r02*sz;
    float m10 = r10*sx, m11 = r11*sy, m12 = r12*sz;
    float m20 = r20*sx, m21 = r21*sy, m22 = r22*sz;

    float a = m00*m00 + m01*m01 + m02*m02;
    float b = m00*m10 + m01*m11 + m02*m12;
    float c = m00*m20 + m01*m21 + m02*m22;
    float d = m10*m10 + m11*m11 + m12*m12;
    float e = m10*m20 + m11*m21 + m12*m22;
    float f = m20*m20 + m21*m21 + m22*m22;

    float A = d*f - e*e;
    float B = c*e - b*f;
    float C = b*e - c*d;
    float det  = a*A + b*B + c*C;
    float idet = L2E / det;            // fold log2e into all quad coeffs

    float n00 = -0.5f * A * idet;
    float n01 = -B * idet;
    float n02 = -C * idet;
    float n11 = -0.5f * (a*f - c*c) * idet;
    float n12 = -(b*c - a*e) * idet;
    float n22 = -0.5f * (a*d - b*b) * idet;

    int bx = (int)floorf((mx - LB) * 64.0f) - 3;
    int by = (int)floorf((my - LB) * 64.0f) - 3;
    int bz = (int)floorf((mz - LB) * 64.0f) - 3;
    unsigned pb = ((unsigned)(bx + 4) << 16) | ((unsigned)(by + 4) << 8) |
                  (unsigned)(bz + 4);

    float sr, cr;
    __sincosf(ph, &sr, &cr);
    float wr = op * cr;
    float wi = op * (sr + pa);

    float fx = LB + 0.5f * VOX - mx;
    float fy = LB + 0.5f * VOX - my;
    float fz = LB + 0.5f * VOX - mz;

    float4* rp = reinterpret_cast<float4*>(rec + (size_t)g * RECSZ);
    rp[0] = make_float4(n00, n01, n02, n11);
    rp[1] = make_float4(n12, n22, fx, fy);
    rp[2] = make_float4(fz, wr, wi, __uint_as_float(pb));
    *bxo = bx; *byo = by; *bzo = bz;
}

// ---------------- Path A: prep with batched (pipelined) bin atomics --------
#define BIN_DECL(K, DX, DY, DZ)                                              \
    const int  tx##K = xlo + (DX), ty##K = ylo + (DY), tz##K = zlo + (DZ);   \
    const bool v##K  = (tx##K <= xhi) && (ty##K <= yhi) && (tz##K <= zhi);   \
    const int  t##K  = (tx##K * NSBA + ty##K) * NSBA + tz##K;                \
    int        i##K  = 0;                                                    \
    if (v##K) i##K = atomicAdd(&cursors[t##K], 1);

#define BIN_STORE(K)                                                         \
    if (v##K && i##K < CAP) list[t##K * CAP + i##K] = g;

__global__ __launch_bounds__(256) void cgr_prep_fused(
    const float* __restrict__ means, const float* __restrict__ opacities,
    const float* __restrict__ scales, const float* __restrict__ rotations,
    const float* __restrict__ phases, const float* __restrict__ phases_add,
    float* __restrict__ rec, int* __restrict__ cursors,
    int* __restrict__ list, int N)
{
    int g = blockIdx.x * 256 + threadIdx.x;
    if (g >= N) return;
    int bx, by, bz;
    build_record(means, opacities, scales, rotations, phases, phases_add,
                 rec, g, &bx, &by, &bz);
    int xlo = max(bx, 0) >> 2, xhi = min(bx + 5, RES - 1) >> 2;
    int ylo = max(by, 0) >> 2, yhi = min(by + 5, RES - 1) >> 2;
    int zlo = max(bz, 0) >> 2, zhi = min(bz + 5, RES - 1) >> 2;

    // phase 1: issue all (<=27) predicated atomics — independent, pipelined
    BIN_DECL( 0,0,0,0) BIN_DECL( 1,0,0,1) BIN_DECL( 2,0,0,2)
    BIN_DECL( 3,0,1,0) BIN_DECL( 4,0,1,1) BIN_DECL( 5,0,1,2)
    BIN_DECL( 6,0,2,0) BIN_DECL( 7,0,2,1) BIN_DECL( 8,0,2,2)
    BIN_DECL( 9,1,0,0) BIN_DECL(10,1,0,1) BIN_DECL(11,1,0,2)
    BIN_DECL(12,1,1,0) BIN_DECL(13,1,1,1) BIN_DECL(14,1,1,2)
    BIN_DECL(15,1,2,0) BIN_DECL(16,1,2,1) BIN_DECL(17,1,2,2)
    BIN_DECL(18,2,0,0) BIN_DECL(19,2,0,1) BIN_DECL(20,2,0,2)
    BIN_DECL(21,2,1,0) BIN_DECL(22,2,1,1) BIN_DECL(23,2,1,2)
    BIN_DECL(24,2,2,0) BIN_DECL(25,2,2,1) BIN_DECL(26,2,2,2)
    // phase 2: stores (counted vmcnt waits as results arrive)
    BIN_STORE( 0) BIN_STORE( 1) BIN_STORE( 2) BIN_STORE( 3) BIN_STORE( 4)
    BIN_STORE( 5) BIN_STORE( 6) BIN_STORE( 7) BIN_STORE( 8) BIN_STORE( 9)
    BIN_STORE(10) BIN_STORE(11) BIN_STORE(12) BIN_STORE(13) BIN_STORE(14)
    BIN_STORE(15) BIN_STORE(16) BIN_STORE(17) BIN_STORE(18) BIN_STORE(19)
    BIN_STORE(20) BIN_STORE(21) BIN_STORE(22) BIN_STORE(23) BIN_STORE(24)
    BIN_STORE(25) BIN_STORE(26)
}

#define EVAL_REC(A0, A1, A2)                                                  \
    do {                                                                      \
        float n00 = A0.x, n01 = A0.y, n02 = A0.z, n11 = A0.w;                 \
        float n12 = A1.x, n22 = A1.y, fx = A1.z, fy = A1.w;                   \
        float fz = A2.x, wr = A2.y, wi = A2.z;                                \
        unsigned pb = __float_as_uint(A2.w);                                  \
        int bx = (int)((pb >> 16) & 255u) - 4;                                \
        int by = (int)((pb >> 8) & 255u) - 4;                                 \
        int bz = (int)(pb & 255u) - 4;                                        \
        bool in = ((unsigned)(vx - bx) < 6u) &                                \
                  ((unsigned)(vy - by) < 6u) &                                \
                  ((unsigned)(vz - bz) < 6u);                                 \
        float dx = fmaf(fvx, VOXC, fx);                                       \
        float dy = fmaf(fvy, VOXC, fy);                                       \
        float dz = fmaf(fvz, VOXC, fz);                                       \
        float arg = dx * (n00 * dx + n01 * dy + n02 * dz)                     \
                  + dy * (n11 * dy + n12 * dz) + dz * (n22 * dz);             \
        float w = in ? exp2f(arg) : 0.0f;                                     \
        accR = fmaf(w, wr, accR);                                             \
        accI = fmaf(w, wi, accI);                                             \
    } while (0)

// ---------------- Path A: LDS-staged eval ----------------
__global__ __launch_bounds__(256) void cgr_eval_lds(
    const float* __restrict__ rec,
    const int* __restrict__ cursors,
    const int* __restrict__ list,
    float* __restrict__ grid)
{
    __shared__ float sbuf[4][64 * RECSZ];   // wave-private 3KB buffers

    const float VOXC = 2.0f / 128.0f;

    // XCD-chunked swizzle: 8192 blocks -> 8 contiguous chunks of 1024
    int bid = blockIdx.x;
    int swz = (bid & 7) * 1024 + (bid >> 3);

    int wave = threadIdx.x >> 6;
    int lane = threadIdx.x & 63;
    int s = swz * 4 + wave;                 // 0..NTILE-1
    int sx = s >> 10;
    int sy = (s >> 5) & 31;
    int sz = s & 31;
    int vx = sx * SB + (lane >> 4);
    int vy = sy * SB + ((lane >> 2) & 3);
    int vz = sz * SB + (lane & 3);
    float fvx = (float)vx, fvy = (float)vy, fvz = (float)vz;

    int cnt = __builtin_amdgcn_readfirstlane(cursors[s]);
    cnt = min(cnt, CAP);
    const int base = s * CAP;
    float* sb = sbuf[wave];

    float accR = 0.0f, accI = 0.0f;

    for (int cs = 0; cs < cnt; cs += 64) {
        int m = min(64, cnt - cs);
        if (lane < m) {
            int id = list[base + cs + lane];
            const float4* rp =
                reinterpret_cast<const float4*>(rec + (size_t)id * RECSZ);
            float4 v0 = rp[0], v1 = rp[1], v2 = rp[2];
            float4* dst = reinterpret_cast<float4*>(sb + lane * RECSZ);
            dst[0] = v0; dst[1] = v1; dst[2] = v2;
        }
        // wave-private LDS: no barrier needed; compiler orders ds ops
        for (int k = 0; k < m; ++k) {
            const float4* rp = reinterpret_cast<const float4*>(sb + k * RECSZ);
            float4 A0 = rp[0], A1 = rp[1], A2 = rp[2];
            EVAL_REC(A0, A1, A2);
        }
    }

    size_t addr = ((size_t)(vx * RES + vy) * RES + vz) * 2;
    *reinterpret_cast<float2*>(grid + addr) = make_float2(accR, accI);
}

// ---------------- Path B (fallback, compact pipeline) ----------------
__global__ __launch_bounds__(256) void cgr_prep_b(
    const float* __restrict__ means, const float* __restrict__ opacities,
    const float* __restrict__ scales, const float* __restrict__ rotations,
    const float* __restrict__ phases, const float* __restrict__ phases_add,
    float* __restrict__ rec, unsigned* __restrict__ basep,
    int* __restrict__ counts, int N)
{
    int g = blockIdx.x * 256 + threadIdx.x;
    if (g >= N) return;
    int bx, by, bz;
    build_record(means, opacities, scales, rotations, phases, phases_add,
                 rec, g, &bx, &by, &bz);
    basep[g] = ((unsigned)(bx + 4) << 16) | ((unsigned)(by + 4) << 8) |
               (unsigned)(bz + 4);
    int xlo = max(bx, 0) >> 2, xhi = min(bx + 5, RES - 1) >> 2;
    int ylo = max(by, 0) >> 2, yhi = min(by + 5, RES - 1) >> 2;
    int zlo = max(bz, 0) >> 2, zhi = min(bz + 5, RES - 1) >> 2;
    for (int tx = xlo; tx <= xhi; ++tx)
        for (int ty = ylo; ty <= yhi; ++ty)
            for (int tz = zlo; tz <= zhi; ++tz)
                atomicAdd(&counts[(tx * NSBA + ty) * NSBA + tz], 1);
}

__global__ __launch_bounds__(1024) void cgr_scan(
    const int* __restrict__ counts, int* __restrict__ offsets,
    int* __restrict__ cursors)
{
    __shared__ int sa[1024], sb2[1024];
    int tid = threadIdx.x;
    int base = tid * 32;
    int local[32];
    int s = 0;
    #pragma unroll
    for (int k = 0; k < 32; ++k) { local[k] = counts[base + k]; s += local[k]; }
    sa[tid] = s;
    __syncthreads();
    int* src = sa; int* dst = sb2;
    for (int dstep = 1; dstep < 1024; dstep <<= 1) {
        int v = src[tid];
        if (tid >= dstep) v += src[tid - dstep];
        dst[tid] = v;
        __syncthreads();
        int* t = src; src = dst; dst = t;
    }
    int excl = src[tid] - s;
    #pragma unroll
    for (int k = 0; k < 32; ++k) {
        offsets[base + k] = excl;
        cursors[base + k] = excl;
        excl += local[k];
    }
    if (tid == 1023) offsets[NTILE] = excl;
}

__global__ __launch_bounds__(256) void cgr_scatter(
    const unsigned* __restrict__ basep, int* __restrict__ cursors,
    int* __restrict__ list, int N)
{
    int g = blockIdx.x * 256 + threadIdx.x;
    if (g >= N) return;
    unsigned pb = basep[g];
    int bx = (int)((pb >> 16) & 255u) - 4;
    int by = (int)((pb >> 8) & 255u) - 4;
    int bz = (int)(pb & 255u) - 4;
    int xlo = max(bx, 0) >> 2, xhi = min(bx + 5, RES - 1) >> 2;
    int ylo = max(by, 0) >> 2, yhi = min(by + 5, RES - 1) >> 2;
    int zlo = max(bz, 0) >> 2, zhi = min(bz + 5, RES - 1) >> 2;
    for (int tx = xlo; tx <= xhi; ++tx)
        for (int ty = ylo; ty <= yhi; ++ty)
            for (int tz = zlo; tz <= zhi; ++tz) {
                int t = (tx * NSBA + ty) * NSBA + tz;
                int idx = atomicAdd(&cursors[t], 1);
                if (idx < LIST_CAP) list[idx] = g;
            }
}

__global__ __launch_bounds__(256) void cgr_eval_compact(
    const float* __restrict__ rec, const int* __restrict__ offsets,
    const int* __restrict__ list, float* __restrict__ grid)
{
    const float VOXC = 2.0f / 128.0f;
    int wave = threadIdx.x >> 6;
    int lane = threadIdx.x & 63;
    int s = blockIdx.x * 4 + wave;
    int sx = s >> 10;
    int sy = (s >> 5) & 31;
    int sz = s & 31;
    int vx = sx * SB + (lane >> 4);
    int vy = sy * SB + ((lane >> 2) & 3);
    int vz = sz * SB + (lane & 3);
    float fvx = (float)vx, fvy = (float)vy, fvz = (float)vz;

    int jb = __builtin_amdgcn_readfirstlane(offsets[s]);
    int je = __builtin_amdgcn_readfirstlane(offsets[s + 1]);

    float accR = 0.0f, accI = 0.0f;
    for (int j = jb; j < je; ++j) {
        int g = __builtin_amdgcn_readfirstlane(list[j]);
        const float4* rp = reinterpret_cast<const float4*>(rec + (size_t)g * RECSZ);
        float4 A0 = rp[0];
        float4 A1 = rp[1];
        float4 A2 = rp[2];
        EVAL_REC(A0, A1, A2);
    }
    size_t addr = ((size_t)(vx * RES + vy) * RES + vz) * 2;
    *reinterpret_cast<float2*>(grid + addr) = make_float2(accR, accI);
}

extern "C" void kernel_launch(void* const* d_in, const int* in_sizes, int n_in,
                              void* d_out, int out_size, void* d_ws, size_t ws_size,
                              hipStream_t stream) {
    const float* means      = (const float*)d_in[0];
    const float* opacities  = (const float*)d_in[1];
    const float* scales     = (const float*)d_in[2];
    const float* rotations  = (const float*)d_in[3];
    const float* phases     = (const float*)d_in[4];
    const float* phases_add = (const float*)d_in[5];
    float* grid = (float*)d_out;

    int N = in_sizes[1];
    int nb = (N + 255) / 256;

    size_t recB  = (size_t)N * RECSZ * sizeof(float);
    size_t curB  = (size_t)NTILE * sizeof(int);
    size_t listB = (size_t)NTILE * CAP * sizeof(int);

    if (ws_size >= recB + curB + listB) {
        // ---- Path A: fused bucket ----
        char* p = (char*)d_ws;
        float* rec    = (float*)p;  p += recB;
        int*   curs   = (int*)p;    p += curB;
        int*   list   = (int*)p;

        (void)hipMemsetAsync(curs, 0, curB, stream);
        cgr_prep_fused<<<nb, 256, 0, stream>>>(means, opacities, scales,
                                               rotations, phases, phases_add,
                                               rec, curs, list, N);
        cgr_eval_lds<<<NTILE / 4, 256, 0, stream>>>(rec, curs, list, grid);
    } else {
        // ---- Path B: compact list ----
        char* p = (char*)d_ws;
        float*    rec     = (float*)p;     p += recB;
        unsigned* basep   = (unsigned*)p;  p += (size_t)N * sizeof(unsigned);
        int*      counts  = (int*)p;       p += curB;
        int*      offsets = (int*)p;       p += (size_t)(NTILE + 1) * sizeof(int);
        int*      curs    = (int*)p;       p += curB;
        int*      list    = (int*)p;

        (void)hipMemsetAsync(counts, 0, curB, stream);
        cgr_prep_b<<<nb, 256, 0, stream>>>(means, opacities, scales, rotations,
                                           phases, phases_add, rec, basep,
                                           counts, N);
        cgr_scan<<<1, 1024, 0, stream>>>(counts, offsets, curs);
        cgr_scatter<<<nb, 256, 0, stream>>>(basep, curs, list, N);
        cgr_eval_compact<<<NTILE / 4, 256, 0, stream>>>(rec, offsets, list, grid);
    }
}